// Round 9
// baseline (78.406 us; speedup 1.0000x reference)
//
#include <hip/hip_runtime.h>
#include <hip/hip_bf16.h>

typedef short bf16x8 __attribute__((ext_vector_type(8)));
typedef float f32x4 __attribute__((ext_vector_type(4)));

typedef __attribute__((address_space(3))) void as3_void;
typedef const __attribute__((address_space(1))) void as1_void;

static constexpr int D = 256;
static constexpr float INV_T = 10.0f;  // 1 / 0.1

__device__ __forceinline__ ushort f2bf(float f) {
  union { float f; unsigned u; } v; v.f = f;
  unsigned r = v.u + 0x7fffu + ((v.u >> 16) & 1u);  // RNE
  return (ushort)(r >> 16);
}

// Kernel 1: L2-normalize rows of images & captions -> bf16; diag logits (fp32).
__global__ __launch_bounds__(256) void normalize_kernel(
    const float* __restrict__ im, const float* __restrict__ cap,
    ushort* __restrict__ imn, ushort* __restrict__ capn,
    float* __restrict__ diag, int N) {
  int tid = blockIdx.x * 256 + threadIdx.x;
  int w = tid >> 6;
  int lane = threadIdx.x & 63;
  if (w >= N) return;
  float4 vi = ((const float4*)(im + (size_t)w * D))[lane];
  float4 vc = ((const float4*)(cap + (size_t)w * D))[lane];
  float ssi = vi.x*vi.x + vi.y*vi.y + vi.z*vi.z + vi.w*vi.w;
  float ssc = vc.x*vc.x + vc.y*vc.y + vc.z*vc.z + vc.w*vc.w;
  #pragma unroll
  for (int m = 1; m < 64; m <<= 1) {
    ssi += __shfl_xor(ssi, m);
    ssc += __shfl_xor(ssc, m);
  }
  float ri = 1.0f / fmaxf(sqrtf(ssi), 1e-12f);
  float rc = 1.0f / fmaxf(sqrtf(ssc), 1e-12f);
  float ax = vi.x*ri, ay = vi.y*ri, az = vi.z*ri, aw = vi.w*ri;
  float cx = vc.x*rc, cy = vc.y*rc, cz = vc.z*rc, cw = vc.w*rc;
  ushort4 ua, uc;
  ua.x = f2bf(ax); ua.y = f2bf(ay); ua.z = f2bf(az); ua.w = f2bf(aw);
  uc.x = f2bf(cx); uc.y = f2bf(cy); uc.z = f2bf(cz); uc.w = f2bf(cw);
  ((ushort4*)(imn + (size_t)w * D))[lane] = ua;
  ((ushort4*)(capn + (size_t)w * D))[lane] = uc;
  float d = ax*cx + ay*cy + az*cz + aw*cw;
  #pragma unroll
  for (int m = 1; m < 64; m <<= 1) d += __shfl_xor(d, m);
  if (lane == 0) diag[w] = d * INV_T;
}

// Epilogue for one finished 128x256 tile: exp + row/col partial sums + stores.
__device__ __forceinline__ void epilogue_tile(
    f32x4 (*acc)[4], int bn_e, int bm, int wm, int wn, int lane, int N,
    float* __restrict__ rowpart, float* __restrict__ colpart) {
  #pragma unroll
  for (int mi = 0; mi < 4; ++mi)
    #pragma unroll
    for (int ni = 0; ni < 4; ++ni)
      #pragma unroll
      for (int r = 0; r < 4; ++r)
        acc[mi][ni][r] = __expf(acc[mi][ni][r] * INV_T);
  // C/D layout: col = lane&15, row = (lane>>4)*4 + r
  bool sb0 = (lane & 1) != 0;
  bool sb1 = (lane & 2) != 0;
  #pragma unroll
  for (int mi = 0; mi < 4; ++mi) {
    float v0 = acc[mi][0][0] + acc[mi][1][0] + acc[mi][2][0] + acc[mi][3][0];
    float v1 = acc[mi][0][1] + acc[mi][1][1] + acc[mi][2][1] + acc[mi][3][1];
    float v2 = acc[mi][0][2] + acc[mi][1][2] + acc[mi][2][2] + acc[mi][3][2];
    float v3 = acc[mi][0][3] + acc[mi][1][3] + acc[mi][2][3] + acc[mi][3][3];
    float h0 = (sb0 ? v1 : v0) + __shfl_xor(sb0 ? v0 : v1, 1);
    float h1 = (sb0 ? v3 : v2) + __shfl_xor(sb0 ? v2 : v3, 1);
    float g  = (sb1 ? h1 : h0) + __shfl_xor(sb1 ? h0 : h1, 2);
    g += __shfl_xor(g, 4);
    g += __shfl_xor(g, 8);
    if ((lane & 12) == 0)
      rowpart[(size_t)(bn_e * 4 + wn) * N + bm * 128 + wm * 64 + mi * 16 +
              (lane >> 4) * 4 + (lane & 3)] = g;
  }
  #pragma unroll
  for (int ni = 0; ni < 4; ++ni) {
    float v = 0.f;
    #pragma unroll
    for (int mi = 0; mi < 4; ++mi)
      #pragma unroll
      for (int r = 0; r < 4; ++r)
        v += acc[mi][ni][r];
    v += __shfl_xor(v, 16); v += __shfl_xor(v, 32);
    if (lane < 16)
      colpart[(size_t)(bm * 2 + wm) * N + bn_e * 256 + wn * 64 + ni * 16 + lane] = v;
  }
}

// Kernel 2: persistent GEMM with register-level read-ahead.
// Grid 256 (1/CU): block = (bm of 64, group of 4); 8 bn-tiles of 128x256 each,
// one 64-body pipeline. A (128 x 256K) resident in 64KB LDS; B in 4 x 16KB
// chunk buffers. Per body (kt): {stage B(kt+3); [epilogue]; read-ahead
// frags(kt+1); 16 MFMA on frags(kt); vmcnt(counted); barrier} -- MFMA operands
// are always >= 1 body old (zero read-latency exposure); vmcnt never drains.
// Buffer safety: stage of chunk g (body g-3) overwrites chunk g-4, whose frag
// reads are separated by body g-4's end barrier. Swizzle: LDS slot (row,unit u)
// holds global unit u^(row&3); pre-swizzled global source, same XOR on reads.
__global__ __launch_bounds__(512) void gemm_exp_kernel(
    const ushort* __restrict__ A, const ushort* __restrict__ Bm,
    float* __restrict__ rowpart, float* __restrict__ colpart, int N) {
  __shared__ ushort As[8][128 * 32];  // 8 x 8 KB  = 64 KB (A resident)
  __shared__ ushort Bs[4][256 * 32];  // 4 x 16 KB = 64 KB (B chunk ring)
  int bm = blockIdx.x >> 2;
  int grp = blockIdx.x & 3;
  int t = threadIdx.x;
  int lane = t & 63;
  int wv = t >> 6;             // 0..7
  int wm = wv >> 2;            // 0..1 : rows [wm*64, +64) of the 128
  int wn = wv & 3;             // 0..3 : cols [wn*64, +64) of the 256

  // stage geometry: thread covers row = wv*16 + (lane>>2) (+128 for B half 1),
  // LDS unit (lane&3); global source unit pre-swizzled ^ (row&3).
  int sunit = (lane & 3) ^ ((lane >> 2) & 3);
  const ushort* agS = A + ((size_t)bm * 128 + wv * 16 + (lane >> 2)) * D + 8 * sunit;

  f32x4 acc[4][4];
  bf16x8 fa0[4], fb0[4], fa1[4], fb1[4];

  int rb = lane & 15;
  int uA = (((lane >> 4) ^ (rb & 3))) * 8;  // swizzled read unit offset (elems)

#define VMWAIT_(n) asm volatile("s_waitcnt vmcnt(" #n ")" ::: "memory")
#define VMWAIT(n) VMWAIT_(n)
#define BARRIER() asm volatile("s_barrier" ::: "memory")

#define STAGE_A(c)                                                           \
  __builtin_amdgcn_global_load_lds((as1_void*)(agS + (c) * 32),              \
      (as3_void*)(&As[c][wv * 512]), 16, 0, 0);

#define STAGE_B(buf, ptr, ch)                                                \
  __builtin_amdgcn_global_load_lds((as1_void*)((ptr) + (ch) * 32),           \
      (as3_void*)(&Bs[buf][wv * 512]), 16, 0, 0);                            \
  __builtin_amdgcn_global_load_lds(                                          \
      (as1_void*)((ptr) + (size_t)128 * D + (ch) * 32),                      \
      (as3_void*)(&Bs[buf][4096 + wv * 512]), 16, 0, 0);

#define READ_A_(FA, c)                                                       \
  { _Pragma("unroll") for (int mi = 0; mi < 4; ++mi)                         \
      FA[mi] = *(const bf16x8*)(&As[c][(wm * 64 + mi * 16 + rb) * 32 + uA]); }

#define READ_B_(FB, b)                                                       \
  { _Pragma("unroll") for (int ni = 0; ni < 4; ++ni)                         \
      FB[ni] = *(const bf16x8*)(&Bs[b][(wn * 64 + ni * 16 + rb) * 32 + uA]); }

  // Body kt: stage B chunk (kt+3) -> buf (kt+3)&3; optional epilogue of the
  // previous tile; read-ahead frags (kt+1); MFMA frags (kt); counted vmcnt;
  // end barrier. CZ=1 restarts the accumulator (C = 0).
#define BODY(KT, FAc, FBc, FAn, FBn, SPTR, SCH, CZ, VMN, EPIF, BNE)          \
  {                                                                          \
    STAGE_B(((KT) + 3) & 3, SPTR, SCH)                                       \
    if (EPIF) epilogue_tile(acc, BNE, bm, wm, wn, lane, N, rowpart, colpart);\
    READ_A_(FAn, ((KT) + 1) & 7)                                             \
    READ_B_(FBn, ((KT) + 1) & 3)                                             \
    __builtin_amdgcn_s_setprio(1);                                           \
    _Pragma("unroll") for (int mi = 0; mi < 4; ++mi)                         \
      _Pragma("unroll") for (int ni = 0; ni < 4; ++ni)                       \
        acc[mi][ni] = __builtin_amdgcn_mfma_f32_16x16x32_bf16(               \
            FAc[mi], FBc[ni],                                                \
            (CZ) ? (f32x4){0.f, 0.f, 0.f, 0.f} : acc[mi][ni], 0, 0, 0);      \
    __builtin_amdgcn_s_setprio(0);                                           \
    VMWAIT(VMN); BARRIER();                                                  \
  }

#define BT(j) (Bm + ((size_t)((grp * 8 + (j)) * 256) + wv * 16 + (lane >> 2)) * D + 8 * sunit)

  // Prologue: A chunks 0..7 (8 loads), B chunks 0,1,2 (6 loads).
  STAGE_A(0) STAGE_A(1) STAGE_A(2) STAGE_A(3)
  STAGE_A(4) STAGE_A(5) STAGE_A(6) STAGE_A(7)
  {
    const ushort* bt0 = BT(0);
    STAGE_B(0, bt0, 0) STAGE_B(1, bt0, 1) STAGE_B(2, bt0, 2)
  }
  VMWAIT(2); BARRIER();          // A + B0 + B1 confirmed; B2 in flight
  READ_A_(fa0, 0) READ_B_(fb0, 0)  // frags for body 0 ("body -1" reads)

  {  // j = 0 (no epilogue)
    const ushort* btc = BT(0);
    const ushort* btn = BT(1);
    BODY(0, fa0, fb0, fa1, fb1, btc, 3, 1, 2, 0, 0)
    BODY(1, fa1, fb1, fa0, fb0, btc, 4, 0, 2, 0, 0)
    BODY(2, fa0, fb0, fa1, fb1, btc, 5, 0, 2, 0, 0)
    BODY(3, fa1, fb1, fa0, fb0, btc, 6, 0, 2, 0, 0)
    BODY(4, fa0, fb0, fa1, fb1, btc, 7, 0, 2, 0, 0)
    BODY(5, fa1, fb1, fa0, fb0, btn, 0, 0, 2, 0, 0)
    BODY(6, fa0, fb0, fa1, fb1, btn, 1, 0, 2, 0, 0)
    BODY(7, fa1, fb1, fa0, fb0, btn, 2, 0, 2, 0, 0)
  }
  for (int j = 1; j < 8; ++j) {
    const ushort* btc = BT(j);
    const ushort* btn = BT(j < 7 ? j + 1 : 7);   // j=7 wrap: valid, never read
    int bne = grp * 8 + j - 1;
    BODY(0, fa0, fb0, fa1, fb1, btc, 3, 1, 8, 1, bne)
    BODY(1, fa1, fb1, fa0, fb0, btc, 4, 0, 8, 0, 0)
    BODY(2, fa0, fb0, fa1, fb1, btc, 5, 0, 2, 0, 0)
    BODY(3, fa1, fb1, fa0, fb0, btc, 6, 0, 2, 0, 0)
    BODY(4, fa0, fb0, fa1, fb1, btc, 7, 0, 2, 0, 0)
    BODY(5, fa1, fb1, fa0, fb0, btn, 0, 0, 2, 0, 0)
    BODY(6, fa0, fb0, fa1, fb1, btn, 1, 0, 2, 0, 0)
    BODY(7, fa1, fb1, fa0, fb0, btn, 2, 0, 2, 0, 0)
  }
  VMWAIT(0);  // retire stray wrap stages
  epilogue_tile(acc, grp * 8 + 7, bm, wm, wn, lane, N, rowpart, colpart);

#undef BODY
#undef BT
#undef READ_A_
#undef READ_B_
#undef STAGE_A
#undef STAGE_B
#undef VMWAIT
#undef VMWAIT_
#undef BARRIER
}

// Kernel 3: coalesced partial reduction (wave per slot residue, LDS combine).
__global__ __launch_bounds__(256) void reduce_kernel(
    const float* __restrict__ rowpart, const float* __restrict__ colpart,
    const float* __restrict__ diag, float* __restrict__ blocksum,
    int N, int NPr, int NPc) {
  __shared__ float redr[4][64], redc[4][64];
  int w = threadIdx.x >> 6, s = threadIdx.x & 63;
  int i = blockIdx.x * 64 + s;
  float rs = 0.f, cs = 0.f;
  for (int k = w; k < NPr; k += 4) rs += rowpart[(size_t)k * N + i];
  for (int k = w; k < NPc; k += 4) cs += colpart[(size_t)k * N + i];
  redr[w][s] = rs; redc[w][s] = cs;
  __syncthreads();
  if (w == 0) {
    float R = redr[0][s] + redr[1][s] + redr[2][s] + redr[3][s];
    float C = redc[0][s] + redc[1][s] + redc[2][s] + redc[3][s];
    float l = logf(R) + logf(C) - 2.0f * diag[i];
    #pragma unroll
    for (int m = 1; m < 64; m <<= 1) l += __shfl_xor(l, m);
    if (s == 0) blocksum[blockIdx.x] = l;
  }
}

// Kernel 4: final mean over 128 block sums
__global__ __launch_bounds__(128) void final_kernel(
    const float* __restrict__ blocksum, float* __restrict__ out, int N) {
  __shared__ float red[2];
  float v = blocksum[threadIdx.x];
  #pragma unroll
  for (int m = 1; m < 64; m <<= 1) v += __shfl_xor(v, m);
  if ((threadIdx.x & 63) == 0) red[threadIdx.x >> 6] = v;
  __syncthreads();
  if (threadIdx.x == 0) out[0] = (red[0] + red[1]) * (0.5f / (float)N);
}

extern "C" void kernel_launch(void* const* d_in, const int* in_sizes, int n_in,
                              void* d_out, int out_size, void* d_ws, size_t ws_size,
                              hipStream_t stream) {
  const float* images = (const float*)d_in[0];
  const float* captions = (const float*)d_in[1];
  int N = in_sizes[0] / D;   // 8192
  int NPr = 128;             // 32 bn-tiles x 4 wn
  int NPc = 128;             // 64 bm-blocks x 2 wm
  char* w = (char*)d_ws;
  size_t off = 0;
  ushort* imn  = (ushort*)(w + off); off += (size_t)N * D * 2;
  ushort* capn = (ushort*)(w + off); off += (size_t)N * D * 2;
  float* diag    = (float*)(w + off); off += (size_t)N * 4;
  float* rowpart = (float*)(w + off); off += (size_t)NPr * N * 4;
  float* colpart = (float*)(w + off); off += (size_t)NPc * N * 4;
  float* blocksum = (float*)(w + off); off += 1024;
  float* out = (float*)d_out;

  normalize_kernel<<<N / 4, 256, 0, stream>>>(images, captions, imn, capn, diag, N);
  gemm_exp_kernel<<<256, 512, 0, stream>>>(imn, capn, rowpart, colpart, N);
  reduce_kernel<<<N / 64, 256, 0, stream>>>(rowpart, colpart, diag, blocksum, N, NPr, NPc);
  final_kernel<<<1, 128, 0, stream>>>(blocksum, out, N);
}